// Round 10
// baseline (2657.265 us; speedup 1.0000x reference)
//
#include <hip/hip_runtime.h>
#include <hip/hip_bf16.h>
#include <math.h>

// ============================================================================
// ResponseFilter — round 12: batched up-front weight conversion.
//
// Round-11 post-mortem: pe/pd->MFMA neutral; GEMM plateau confirmed across
// 6 structural variants (schedule x tile x occupancy x swizzle, all +-4%,
// MfmaUtil pinned ~21%). Per-block math: 24 K-steps x 4200cyc vs 1030cyc
// MFMA -> cache-latency on the 32KB/step staging burst at 1 blk/CU
// (register-bound: 88 VGPR + 128 AGPR acc = 216 -> 2 waves/SIMD). Stop
// churning GEMM structure. This round removes the last identifiable waste:
// 18 small weight-conversion launches interleaved between GEMMs -> ONE
// w2bf_layer kernel per layer (4 tensors batched), all up-front, weights
// parked in the dead new_emb scratch of d_out after X (44.8MB, consumed
// before newemb_kernel rewrites the region). GEMM chain now back-to-back.
// gemm_mfma / attn / ln / epilogues identical to round 11 (verified).
// ============================================================================

#define B_  16
#define T_  32
#define L_  64
#define D_  768
#define H_  12
#define F_  2048
#define ZR_ 100
#define NP_ 512
#define EPS_ 1e-5f

// meta int offsets (d_ws as int*)
#define MI_NTOT  0
#define MI_NRESP 8
#define MI_OFF   32
#define MI_BIDX  64
#define MI_TIDX  576
#define MI_NODE  1088

// ws float offsets
#define WS_BIAS2 2048
#define WS_EMEAN 34816
#define WS_S     428032
#define WS_BIG   1313280   // bf16 QKV/hidden region; bf16 Z overlay (enc->dec)

// d_out float offsets (flat tuple: oh[512], ext_mask[32768], n_ext_adv[1],
// new_tree_lens[16], new_emb[25165824], new_msk[32768])
#define OUT_OH   0
#define OUT_EXT  512
#define OUT_NEA  33280
#define OUT_NTL  33281
#define OUT_NEMB 33297
#define OUT_NMSK 25199121
#define OUT_XSCR 33300   // bf16 X scratch (16B aligned), 32768*768 ushorts

// weight block (bf16) in d_out scratch, right after X (ushort offsets from WB)
// X ends at byte 50,464,848 (16B aligned); WB spans 44.83MB, ends at float
// offset 23,823,124 < new_emb end 25,199,121 -> safe, rewritten only by
// newemb_kernel after all weights are consumed.
#define WB_LAYER  5505024   // per layer: qkv 1769472 | out 589824 | w1 1572864 | w2 1572864
#define WB_QKV    0
#define WB_OUT    1769472
#define WB_W1     2359296
#define WB_W2     3932160
#define WB_PE     22020096  // 256*768
#define WB_PD     22216704  // 768*256
#define WB_PEB    22413312  // 256 floats (512 ushorts), 16B aligned

typedef __attribute__((ext_vector_type(8))) short short8;
typedef __attribute__((ext_vector_type(4))) float f32x4;

__device__ inline float bf2f(unsigned s) {
  return __uint_as_float((s & 0xffffu) << 16);
}
__device__ inline unsigned short f2bf(float x) {
  unsigned u = __float_as_uint(x);
  u += 0x7fffu + ((u >> 16) & 1u);      // round-to-nearest-even
  return (unsigned short)(u >> 16);
}
__device__ inline unsigned pack2(float a, float b) {
  return (unsigned)f2bf(a) | ((unsigned)f2bf(b) << 16);
}

// ---------------------------------------------------------------------------
__global__ void meta_kernel(const int* __restrict__ tl, int* __restrict__ mi) {
  if (threadIdx.x != 0) return;
  int off = 0;
  for (int b = 0; b < B_; b++) {
    int nr = tl[b] - 1;
    mi[MI_NRESP + b] = nr;
    mi[MI_OFF + b] = off;
    off += nr;
  }
  mi[MI_NTOT] = off;
  for (int j = 0; j < NP_; j++) {
    int b = -1, t = 0;
    if (j < off) {
      b = 0;
      while (b + 1 < B_ && j >= mi[MI_OFF + b + 1]) b++;
      t = j - mi[MI_OFF + b] + 1;
    }
    mi[MI_BIDX + j] = b;
    mi[MI_TIDX + j] = t;
  }
}

// ---------------------------------------------------------------------------
// one layer's 4 weight tensors fp32 -> bf16, batched (5,505,024 elems)
__global__ __launch_bounds__(256) void w2bf_layer(
    const float* __restrict__ qkv, const float* __restrict__ ow,
    const float* __restrict__ w1, const float* __restrict__ w2,
    unsigned short* __restrict__ dst) {
  const int e = (blockIdx.x * 256 + threadIdx.x) * 4;
  const float* src; int off;
  if (e < WB_OUT)      { src = qkv; off = e; }
  else if (e < WB_W1)  { src = ow;  off = e - WB_OUT; }
  else if (e < WB_W2)  { src = w1;  off = e - WB_W1; }
  else                 { src = w2;  off = e - WB_W2; }
  float4 v = *(const float4*)(src + off);
  uint2 pk; pk.x = pack2(v.x, v.y); pk.y = pack2(v.z, v.w);
  *(uint2*)(dst + e) = pk;
}

// fp32 [nr][nc] -> bf16 [NR][NC] zero-padded (NR*NC mult of 1024, NC mult 4)
__global__ __launch_bounds__(256) void padw2bf_kernel(
    const float* __restrict__ W, int nr, int nc,
    unsigned short* __restrict__ o, int NC) {
  const int e = (blockIdx.x * 256 + threadIdx.x) * 4;
  const int r = e / NC, c = e % NC;
  float v[4];
  #pragma unroll
  for (int j = 0; j < 4; j++)
    v[j] = (r < nr && c + j < nc) ? W[(size_t)r * nc + c + j] : 0.f;
  uint2 pk; pk.x = pack2(v[0], v[1]); pk.y = pack2(v[2], v[3]);
  *(uint2*)(o + e) = pk;
}

// pad bias to 256 floats (zeros beyond n)
__global__ void padbias_kernel(const float* __restrict__ b, int n,
                               float* __restrict__ o) {
  const int t = threadIdx.x;
  o[t] = (t < n) ? b[t] : 0.f;
}

// ---------------------------------------------------------------------------
// X[j,l,:] bf16 = reply embedding (zero for padded j); bias2 = mask or -1e30
__global__ __launch_bounds__(192) void gather_kernel(
    const float* __restrict__ emb, const float* __restrict__ am,
    const int* __restrict__ mi, unsigned short* __restrict__ X,
    float* __restrict__ bias2) {
  const int blk = blockIdx.x;          // j*64 + l
  const int j = blk >> 6, l = blk & 63;
  const int ntot = mi[MI_NTOT];
  const int t = threadIdx.x;
  float4 v = make_float4(0.f, 0.f, 0.f, 0.f);
  if (j < ntot) {
    const int b = mi[MI_BIDX + j], tt = mi[MI_TIDX + j];
    v = ((const float4*)(emb + (size_t)((b * T_ + tt) * L_ + l) * D_))[t];
    if (t == 0) bias2[blk] = am[(b * T_ + tt) * L_ + l];
  } else {
    if (t == 0) bias2[blk] = -1e30f;
  }
  uint2 pk; pk.x = pack2(v.x, v.y); pk.y = pack2(v.z, v.w);
  *(uint2*)(X + (size_t)blk * D_ + t * 4) = pk;
}

// ---------------------------------------------------------------------------
__global__ __launch_bounds__(256) void emean_kernel(const unsigned short* __restrict__ X,
                                                    float* __restrict__ em) {
  const int j = blockIdx.x;
  int d = threadIdx.x;
  for (int c = 0; c < 3; c++, d += 256) {
    const unsigned short* p = X + (size_t)j * L_ * D_ + d;
    float s = 0.f;
    for (int l = 0; l < L_; l++) s += bf2f(p[l * D_]);
    em[j * D_ + d] = s * (1.f / 64.f);
  }
}

// ---------------------------------------------------------------------------
__device__ inline float blockSum256(float v, float* red) {
  #pragma unroll
  for (int o = 32; o > 0; o >>= 1) v += __shfl_down(v, o);
  const int lane = threadIdx.x & 63, wid = threadIdx.x >> 6;
  __syncthreads();
  if (lane == 0) red[wid] = v;
  __syncthreads();
  return red[0] + red[1] + red[2] + red[3];
}

// in-place LN, wave-per-row (4 rows/block, no barriers); skips padded rows
__global__ __launch_bounds__(256) void ln_kernel(unsigned short* __restrict__ X,
                                                 const float* __restrict__ g,
                                                 const float* __restrict__ bb,
                                                 const int* __restrict__ mi) {
  const int row = blockIdx.x * 4 + (threadIdx.x >> 6);
  if (row >= mi[MI_NTOT] * L_) return;
  const int lane = threadIdx.x & 63;
  unsigned short* p = X + (size_t)row * D_;
  float v[12];
  #pragma unroll
  for (int c = 0; c < 3; c++) {
    uint2 u = *(const uint2*)(p + lane * 4 + c * 256);
    v[c * 4 + 0] = bf2f(u.x); v[c * 4 + 1] = bf2f(u.x >> 16);
    v[c * 4 + 2] = bf2f(u.y); v[c * 4 + 3] = bf2f(u.y >> 16);
  }
  float s = 0.f;
  #pragma unroll
  for (int i = 0; i < 12; i++) s += v[i];
  #pragma unroll
  for (int o = 32; o > 0; o >>= 1) s += __shfl_xor(s, o);
  const float m = s * (1.f / 768.f);
  float q = 0.f;
  #pragma unroll
  for (int i = 0; i < 12; i++) { v[i] -= m; q += v[i] * v[i]; }
  #pragma unroll
  for (int o = 32; o > 0; o >>= 1) q += __shfl_xor(q, o);
  const float r = rsqrtf(q * (1.f / 768.f) + EPS_);
  #pragma unroll
  for (int c = 0; c < 3; c++) {
    const int d = lane * 4 + c * 256;
    float4 gv = *(const float4*)(g + d);
    float4 bv = *(const float4*)(bb + d);
    uint2 pk;
    pk.x = pack2(v[c * 4 + 0] * r * gv.x + bv.x, v[c * 4 + 1] * r * gv.y + bv.y);
    pk.y = pack2(v[c * 4 + 2] * r * gv.z + bv.z, v[c * 4 + 3] * r * gv.w + bv.w);
    *(uint2*)(p + d) = pk;
  }
}

// ---------------------------------------------------------------------------
// MFMA bf16 GEMM: C[M,N] = [C +] act(A @ W^T + bias). 256x256 tile, 512 thr
// (8 waves 2x4, wave tile 128x64 via 8x4 of 16x16x32 MFMA). K mult of 32,
// N mult of 256. BK=32, two LDS buffers (64 KB). Per K-step: ONE
// {vmcnt(0); s_barrier}, then stage step i+1 into buf[(i+1)&1] (its last
// readers, step i-1, precede barrier(i) in every wave -> race-free), then
// free-running compute of step i (12 ds_read_b128 + 32 MFMA per wave,
// compiler-scheduled waits, setprio around MFMAs).
// LDS k-group XOR swizzle: slot (row, sp) holds kg = sp ^ ((row>>1)&3).
// ACT: 0 none, 1 relu, 2 tanh. Epilogue: two 64x64 passes via per-wave 8KB
// LDS slice -> coalesced short8 stores (+ residual add at readback for ADD).
template <int ACT, bool ADD>
__global__ __launch_bounds__(512) void gemm_mfma(
    const unsigned short* __restrict__ A, int lda, int K,
    const unsigned short* __restrict__ W, int ldw,
    const float* __restrict__ bias,
    unsigned short* __restrict__ C, int ldc,
    const int* __restrict__ mi) {
  const int rows = mi[MI_NTOT] * 64;
  const int row0 = blockIdx.x * 256;
  if (row0 >= rows) return;
  const int col0 = blockIdx.y * 256;
  __shared__ unsigned short Sh[2 * 16384];   // 2 dbuf x (A 16KB + B 16KB) = 64KB
  const int t = threadIdx.x;
  const int lane = t & 63, w = t >> 6;        // 8 waves
  const int wr = w >> 2, wc = w & 3;          // 2x4 wave grid, tile 128x64
  const int quad = lane >> 4, l15 = lane & 15;
  f32x4 acc[8][4];
  #pragma unroll
  for (int i = 0; i < 8; i++)
    #pragma unroll
    for (int j = 0; j < 4; j++) acc[i][j] = (f32x4){0.f, 0.f, 0.f, 0.f};

  // per-lane staging coords (2 chunks per wave per matrix per step;
  // chunk = 64 lanes x 16B = 1KB; 16 chunks cover 256 rows x 32 k)
  int schunk[2];
  const unsigned short* gA[2];
  const unsigned short* gB[2];
  #pragma unroll
  for (int r = 0; r < 2; r++) {
    const int c = r * 8 + w;
    const int g = c * 64 + lane;
    const int row = g >> 2, slot = g & 3;
    const int kg = slot ^ ((row >> 1) & 3);
    schunk[r] = c;
    gA[r] = A + (size_t)(row0 + row) * lda + kg * 8;
    gB[r] = W + (size_t)(col0 + row) * ldw + kg * 8;
  }
  // fragment LDS offsets (ushorts)
  int aoff[8], boff[4];
  #pragma unroll
  for (int m = 0; m < 8; m++) {
    const int ar = wr * 128 + m * 16 + l15;
    aoff[m] = ar * 32 + (quad ^ ((ar >> 1) & 3)) * 8;
  }
  #pragma unroll
  for (int n = 0; n < 4; n++) {
    const int bn = wc * 64 + n * 16 + l15;
    boff[n] = bn * 32 + (quad ^ ((bn >> 1) & 3)) * 8;
  }

#define STG(bi_, kk_)                                                          \
  { unsigned short* base_ = Sh + (bi_) * 16384;                                \
    _Pragma("unroll")                                                          \
    for (int r = 0; r < 2; r++) {                                              \
      __builtin_amdgcn_global_load_lds(                                        \
          (const __attribute__((address_space(1))) void*)(gA[r] + (kk_)),      \
          (__attribute__((address_space(3))) void*)(base_ + schunk[r] * 512),  \
          16, 0, 0);                                                           \
      __builtin_amdgcn_global_load_lds(                                        \
          (const __attribute__((address_space(1))) void*)(gB[r] + (kk_)),      \
          (__attribute__((address_space(3))) void*)(base_ + 8192 +             \
                                                    schunk[r] * 512),          \
          16, 0, 0);                                                           \
    } }

  const int NS = K >> 5;     // K-steps of 32
  STG(0, 0);
  for (int i = 0; i < NS; i++) {
    asm volatile("s_waitcnt vmcnt(0)\ns_barrier" ::: "memory");
    if (i + 1 < NS) STG((i + 1) & 1, (i + 1) * 32);
    const unsigned short* SA = Sh + (i & 1) * 16384;
    const unsigned short* SB = SA + 8192;
    short8 bfr[4];
    #pragma unroll
    for (int n = 0; n < 4; n++) bfr[n] = *(const short8*)(SB + boff[n]);
    __builtin_amdgcn_s_setprio(1);
    #pragma unroll
    for (int m = 0; m < 8; m++) {
      short8 am = *(const short8*)(SA + aoff[m]);
      #pragma unroll
      for (int n = 0; n < 4; n++)
        acc[m][n] = __builtin_amdgcn_mfma_f32_16x16x32_bf16(am, bfr[n],
                                                            acc[m][n], 0, 0, 0);
    }
    __builtin_amdgcn_s_setprio(0);
  }
  __syncthreads();           // LDS now dead -> reuse as epilogue bounce
#undef STG

  // epilogue: C/D layout col = lane&15, row = quad*4 + reg. Two 64x64 passes
  // per wave through its private 8KB slice, then coalesced short8 stores
  // (8 per lane per pass). Residual add (ADD) at readback.
  unsigned short* slice = Sh + w * 4096;
  float bv[4];
  #pragma unroll
  for (int n = 0; n < 4; n++) bv[n] = bias[col0 + wc * 64 + n * 16 + l15];
  #pragma unroll
  for (int p = 0; p < 2; p++) {
    #pragma unroll
    for (int mm = 0; mm < 4; mm++) {
      #pragma unroll
      for (int reg = 0; reg < 4; reg++) {
        const int r64 = mm * 16 + quad * 4 + reg;
        #pragma unroll
        for (int n = 0; n < 4; n++) {
          float x = acc[p * 4 + mm][n][reg] + bv[n];
          if (ACT == 1) x = fmaxf(x, 0.f);
          if (ACT == 2) x = tanhf(x);
          slice[r64 * 64 + n * 16 + l15] = f2bf(x);
        }
      }
    }
    unsigned short* crow =
        C + (size_t)(row0 + wr * 128 + p * 64) * ldc + col0 + wc * 64;
    #pragma unroll
    for (int i = 0; i < 8; i++) {
      const int j = i * 64 + lane;           // 16B chunk 0..511 of 64x64 tile
      const int r64 = j >> 3, c8 = (j & 7) * 8;
      short8 v = *(const short8*)(slice + j * 8);
      unsigned short* cp = crow + (size_t)r64 * ldc + c8;
      if (ADD) {
        short8 cv = *(const short8*)cp;
        #pragma unroll
        for (int e = 0; e < 8; e++)
          v[e] = (short)f2bf(bf2f((unsigned short)v[e]) +
                             bf2f((unsigned short)cv[e]));
      }
      *(short8*)cp = v;
    }
  }
}

// ---------------------------------------------------------------------------
// MFMA attention, KV-resident: one block per (l, h), 8 waves (512 thr).
// Stage ALL K (global_load_lds, pre-swizzled source -> linear LDS) and V^T
// (manual transpose scatter) once; single barrier; then each wave free-runs
// q-tiles (16 rows/wave, 128/block) x kv-tiles with zero global loads and
// zero barriers (P staging per-wave). O bf16 overwrites Q columns of QKV
// (disjoint from staged K/V columns; each wave owns its rows -> race-free).
// LDS tile swizzle: elem(row,col) at row*64 + ((col>>3)^(row&7))*8 + (col&7).
__global__ __launch_bounds__(512) void attn_kernel(
    unsigned short* __restrict__ QKV, const float* __restrict__ bias2,
    const int* __restrict__ mi) {
  const int ntot = mi[MI_NTOT];
  const int l = blockIdx.x, h = blockIdx.y;
  const int ntk = (ntot + 63) >> 6;     // kv tiles (padded keys masked by bias)
  __shared__ unsigned short Ks[512 * 64];   // K rows [m][d], swizzled
  __shared__ unsigned short Vt[8 * 4096];   // per-tile V^T [d][m], swizzled
  __shared__ unsigned short Ps[8][1024];    // per-wave P / O-bounce
  __shared__ float bs[512];                 // bias column for this l
  const int t = threadIdx.x;
  const int lane = t & 63, w = t >> 6;
  const int quad = lane >> 4, l15 = lane & 15;

  // ---- stage K: linear LDS dst, source chunk pre-swizzled so slot g of row
  // m holds chunk g ^ (m&7) (matches the ds_read swizzle below)
  {
    const int sub = lane >> 3;              // low 3 bits of m
    const int cc = (lane & 7) ^ sub;        // source chunk for this slot
    for (int it = 0; it < ntk; it++) {
      const int m = it * 64 + w * 8 + sub;
      const unsigned short* src =
          QKV + (size_t)(m * L_ + l) * 2304 + 768 + h * 64 + cc * 8;
      __builtin_amdgcn_global_load_lds(
          (const __attribute__((address_space(1))) void*)src,
          (__attribute__((address_space(3))) void*)(Ks + it * 4096 + w * 512),
          16, 0, 0);
    }
  }
  // ---- stage V transposed: thread t -> m = t&63, d in [(t>>6)*8, +8)
  {
    const int m = t & 63;
    const int d0 = (t >> 6) * 8;
    for (int mt = 0; mt < ntk; mt++) {
      short8 v = *(const short8*)(
          QKV + (size_t)((mt * 64 + m) * L_ + l) * 2304 + 1536 + h * 64 + d0);
      #pragma unroll
      for (int i = 0; i < 8; i++) {
        const int d = d0 + i;
        Vt[mt * 4096 + d * 64 + (((m >> 3) ^ (d & 7)) * 8) + (m & 7)] =
            (unsigned short)v[i];
      }
    }
  }
  // ---- stage bias column (padded m already -1e30 from gather)
  bs[t] = bias2[t * 64 + l];
  __syncthreads();

  const int nqt = (ntot + 127) >> 7;
  for (int qt = 0; qt < nqt; qt++) {
    const int qbase = qt * 128 + w * 16;
    if (qbase >= ntot) continue;

    // Q A-frags direct from global (2 x 16B per lane)
    short8 af[2];
    #pragma unroll
    for (int kc = 0; kc < 2; kc++)
      af[kc] = *(const short8*)(
          QKV + (size_t)((qbase + l15) * L_ + l) * 2304 + h * 64 + (kc * 4 + quad) * 8);

    f32x4 oa[4];
    float runmax[4], runsum[4];
    #pragma unroll
    for (int f = 0; f < 4; f++) oa[f] = (f32x4){0.f, 0.f, 0.f, 0.f};
    #pragma unroll
    for (int r2 = 0; r2 < 4; r2++) { runmax[r2] = -3.0e38f; runsum[r2] = 0.f; }

    for (int mt = 0; mt < ntk; mt++) {
      // ---- S = Q @ K^T  (C layout: row q = quad*4+reg, col m = cb*16+l15)
      f32x4 sv[4];
      #pragma unroll
      for (int cb = 0; cb < 4; cb++) {
        sv[cb] = (f32x4){0.f, 0.f, 0.f, 0.f};
        const int mrow = mt * 64 + cb * 16 + l15;
        #pragma unroll
        for (int kc = 0; kc < 2; kc++) {
          short8 bk = *(const short8*)(
              Ks + mrow * 64 + (((kc * 4 + quad) ^ (mrow & 7)) * 8));
          sv[cb] = __builtin_amdgcn_mfma_f32_16x16x32_bf16(af[kc], bk, sv[cb], 0, 0, 0);
        }
      }

      // ---- online softmax (state per q-row = quad*4+reg)
      float bj[4];
      #pragma unroll
      for (int cb = 0; cb < 4; cb++) bj[cb] = bs[mt * 64 + cb * 16 + l15];
      float pj[4][4];   // [cb][reg]
      #pragma unroll
      for (int cb = 0; cb < 4; cb++)
        #pragma unroll
        for (int r2 = 0; r2 < 4; r2++) pj[cb][r2] = sv[cb][r2] * 0.125f + bj[cb];
      float tmax[4];
      #pragma unroll
      for (int r2 = 0; r2 < 4; r2++)
        tmax[r2] = fmaxf(fmaxf(pj[0][r2], pj[1][r2]), fmaxf(pj[2][r2], pj[3][r2]));
      #pragma unroll
      for (int o2 = 1; o2 < 16; o2 <<= 1)
        #pragma unroll
        for (int r2 = 0; r2 < 4; r2++) tmax[r2] = fmaxf(tmax[r2], __shfl_xor(tmax[r2], o2));
      float tsum[4];
      #pragma unroll
      for (int r2 = 0; r2 < 4; r2++) {
        const float nmax = fmaxf(runmax[r2], tmax[r2]);
        const float alpha = __expf(runmax[r2] - nmax);
        runmax[r2] = nmax;
        float s0 = 0.f;
        #pragma unroll
        for (int cb = 0; cb < 4; cb++) { pj[cb][r2] = __expf(pj[cb][r2] - nmax); s0 += pj[cb][r2]; }
        tsum[r2] = s0;
        runsum[r2] *= alpha;
        #pragma unroll
        for (int f = 0; f < 4; f++) oa[f][r2] *= alpha;
      }
      #pragma unroll
      for (int o2 = 1; o2 < 16; o2 <<= 1)
        #pragma unroll
        for (int r2 = 0; r2 < 4; r2++) tsum[r2] += __shfl_xor(tsum[r2], o2);
      #pragma unroll
      for (int r2 = 0; r2 < 4; r2++) runsum[r2] += tsum[r2];

      // ---- P -> per-wave LDS (A-operand layout, bf16)
      #pragma unroll
      for (int cb = 0; cb < 4; cb++) {
        const int m = cb * 16 + l15;
        #pragma unroll
        for (int r2 = 0; r2 < 4; r2++) {
          const int q = quad * 4 + r2;
          Ps[w][q * 64 + (((m >> 3) ^ (q & 7)) * 8) + (m & 7)] = f2bf(pj[cb][r2]);
        }
      }
      // ---- O += P @ V
      short8 pa[2];
      #pragma unroll
      for (int kc = 0; kc < 2; kc++)
        pa[kc] = *(const short8*)(
            &Ps[w][l15 * 64 + (((kc * 4 + quad) ^ (l15 & 7)) * 8)]);
      #pragma unroll
      for (int f = 0; f < 4; f++) {
        const int d = f * 16 + l15;
        #pragma unroll
        for (int kc = 0; kc < 2; kc++) {
          short8 bv = *(const short8*)(
              Vt + mt * 4096 + d * 64 + (((kc * 4 + quad) ^ (d & 7)) * 8));
          oa[f] = __builtin_amdgcn_mfma_f32_16x16x32_bf16(pa[kc], bv, oa[f], 0, 0, 0);
        }
      }
    }

    // ---- epilogue: normalize, bounce through per-wave Ps, 16B stores
    #pragma unroll
    for (int r2 = 0; r2 < 4; r2++) {
      const float inv = 1.f / runsum[r2];
      const int q = quad * 4 + r2;
      #pragma unroll
      for (int f = 0; f < 4; f++)
        Ps[w][q * 64 + f * 16 + l15] = f2bf(oa[f][r2] * inv);
    }
    #pragma unroll
    for (int i = 0; i < 2; i++) {
      const int j = lane + i * 64;          // 16B chunk index 0..127
      const int q = j >> 3, c8 = j & 7;
      short8 v = *(const short8*)(&Ps[w][j * 8]);
      *(short8*)(QKV + (size_t)((qbase + q) * L_ + l) * 2304 + h * 64 + c8 * 8) = v;
    }
  }
}

// ---------------------------------------------------------------------------
__global__ __launch_bounds__(256) void score_kernel(const unsigned short* __restrict__ X,
                                                    const float* __restrict__ em,
                                                    float* __restrict__ Sv) {
  const int j = blockIdx.x;
  const int t = threadIdx.x;
  __shared__ float red[4];
  float part = 0.f;
  for (int c = 0; c < 3; c++) {
    const int d = t + c * 256;
    const unsigned short* p = X + (size_t)j * L_ * D_ + d;
    float s = 0.f;
    for (int l = 0; l < L_; l++) s += bf2f(p[l * D_]);
    const float diff = s * (1.f / 64.f) - em[j * D_ + d];
    part += diff * diff;
  }
  const float tot = blockSum256(part, red);
  if (t == 0) Sv[j] = tot;
}

// ---------------------------------------------------------------------------
__global__ __launch_bounds__(256) void finalize_kernel(const float* __restrict__ Sv,
                                                       int* __restrict__ mi,
                                                       float* __restrict__ out) {
  const int t = threadIdx.x;
  if (t < B_) {
    const int nr = mi[MI_NRESP + t];
    float best = 3.0e38f; int bi = 0;
    for (int j = 0; j < nr; j++) {
      const float v = Sv[j];
      if (v < best) { best = v; bi = j; }
    }
    mi[MI_NODE + t] = bi + 1;
    int next = nr / 20; if (next < 1) next = 1;
    out[OUT_NTL + t] = (float)(1 + next);
  }
  if (t == 0) out[OUT_NEA] = 0.f;
  __syncthreads();
  for (int idx = t; idx < B_ * T_; idx += 256) {
    const int b = idx >> 5, tt = idx & 31;
    out[OUT_OH + idx] = (tt == 0 || tt == mi[MI_NODE + b]) ? 1.f : 0.f;
  }
}

// ---------------------------------------------------------------------------
__global__ __launch_bounds__(256) void maskout_kernel(const float* __restrict__ am,
                                                      const int* __restrict__ mi,
                                                      float* __restrict__ out) {
  const int idx = blockIdx.x * 256 + threadIdx.x;
  const int b = idx >> 11, rem = idx & 2047;
  const int tt = rem >> 6, l = rem & 63;
  const int node = mi[MI_NODE + b];
  out[OUT_EXT + idx] = (tt == 0 || tt == node) ? 1.f : 0.f;
  float nm;
  if (tt == 0)      nm = am[(b * T_) * L_ + l];
  else if (tt == 1) nm = am[(b * T_ + node) * L_ + l];
  else              nm = 0.f;
  out[OUT_NMSK + idx] = nm;
}

// ---------------------------------------------------------------------------
__global__ __launch_bounds__(192) void newemb_kernel(const float* __restrict__ emb,
                                                     const int* __restrict__ mi,
                                                     float* __restrict__ out) {
  const int blk = blockIdx.x;
  const int b = blk >> 11, rem = blk & 2047;
  const int tt = rem >> 6, l = rem & 63;
  const int srct = (tt == 1) ? mi[MI_NODE + b] : 0;
  const float4 v = ((const float4*)(emb + (size_t)((b * T_ + srct) * L_ + l) * D_))[threadIdx.x];
  float* dst = out + OUT_NEMB + (size_t)blk * D_ + threadIdx.x * 4;
  dst[0] = v.x; dst[1] = v.y; dst[2] = v.z; dst[3] = v.w;
}

// ===========================================================================
extern "C" void kernel_launch(void* const* d_in, const int* in_sizes, int n_in,
                              void* d_out, int out_size, void* d_ws, size_t ws_size,
                              hipStream_t stream) {
  (void)in_sizes; (void)n_in; (void)out_size; (void)ws_size;
  const int*   tl  = (const int*)d_in[0];
  const float* emb = (const float*)d_in[1];
  const float* am  = (const float*)d_in[2];
  const float* P[28];
  for (int i = 0; i < 28; i++) P[i] = (const float*)d_in[3 + i];

  float* wsf   = (float*)d_ws;
  int*   mi    = (int*)d_ws;
  float* bias2 = wsf + WS_BIAS2;
  float* emean = wsf + WS_EMEAN;
  float* Sv    = wsf + WS_S;
  unsigned short* BIG = (unsigned short*)(wsf + WS_BIG);
  unsigned short* Z16 = BIG;                        // bf16 Z overlay (enc->dec)
  float* out   = (float*)d_out;
  unsigned short* X = (unsigned short*)(out + OUT_XSCR);  // bf16 residual
  unsigned short* WB = X + (size_t)NP_ * 64 * D_;   // bf16 weights, after X

  // ---- all weight conversions batched up-front (dead new_emb scratch)
  for (int j = 0; j < 4; j++) {
    const int s = j >> 1, i = j & 1;
    const float* const* q = P + s * 12;
    w2bf_layer<<<WB_LAYER / 1024, 256, 0, stream>>>(
        q[0] + (size_t)i * 3 * D_ * D_, q[2] + (size_t)i * D_ * D_,
        q[6] + (size_t)i * F_ * D_, q[8] + (size_t)i * D_ * F_,
        WB + (size_t)j * WB_LAYER);
  }
  padw2bf_kernel<<<(256 * D_) / 1024, 256, 0, stream>>>(
      P[24], ZR_, D_, WB + WB_PE, D_);
  padw2bf_kernel<<<(D_ * 256) / 1024, 256, 0, stream>>>(
      P[26], D_, ZR_, WB + WB_PD, 256);
  padbias_kernel<<<1, 256, 0, stream>>>(P[25], ZR_, (float*)(WB + WB_PEB));

  meta_kernel<<<1, 64, 0, stream>>>(tl, mi);
  gather_kernel<<<NP_ * L_, 192, 0, stream>>>(emb, am, mi, X, bias2);
  emean_kernel<<<NP_, 256, 0, stream>>>(X, emean);

  const int RTM = NP_ * 64 / 256;  // 128 row tiles (256 rows each)
  const int LNB = NP_ * L_ / 4;    // 8192 ln blocks (4 rows each)
  for (int s = 0; s < 2; s++) {
    const float* const* q = P + s * 12;
    for (int i = 0; i < 2; i++) {
      const unsigned short* Wl = WB + (size_t)(s * 2 + i) * WB_LAYER;
      // QKV: X -> BIG [rows, 2304]
      gemm_mfma<0, false><<<dim3(RTM, 9), 512, 0, stream>>>(
          X, D_, D_, Wl + WB_QKV, D_, q[1] + i * 3 * D_, BIG, 3 * D_, mi);
      attn_kernel<<<dim3(L_, H_), 512, 0, stream>>>(BIG, bias2, mi);
      // out-proj: O (Q cols of BIG, lda=2304) -> += X
      gemm_mfma<0, true><<<dim3(RTM, 3), 512, 0, stream>>>(
          BIG, 3 * D_, D_, Wl + WB_OUT, D_, q[3] + i * D_, X, D_, mi);
      ln_kernel<<<LNB, 256, 0, stream>>>(X, q[4] + i * D_, q[5] + i * D_, mi);
      // FFN1: X -> hidden BIG [rows, 2048] (relu)
      gemm_mfma<1, false><<<dim3(RTM, 8), 512, 0, stream>>>(
          X, D_, D_, Wl + WB_W1, D_, q[7] + i * F_, BIG, F_, mi);
      // FFN2: hidden -> += X
      gemm_mfma<0, true><<<dim3(RTM, 3), 512, 0, stream>>>(
          BIG, F_, F_, Wl + WB_W2, F_, q[9] + i * D_, X, D_, mi);
      ln_kernel<<<LNB, 256, 0, stream>>>(X, q[10] + i * D_, q[11] + i * D_, mi);
    }
    if (s == 0) {
      // pe: z = tanh(X @ pe_w^T + pe_b) via MFMA, padded N=256 (rows >=100
      // of padded weight are zero, pad bias zero -> padded z cols = 0).
      // Z16 bf16 [rows][256] overlays BIG (dead FFN-hidden here).
      gemm_mfma<2, false><<<dim3(RTM, 1), 512, 0, stream>>>(
          X, D_, D_, WB + WB_PE, D_, (const float*)(WB + WB_PEB),
          Z16, 256, mi);
      // pd: zd = tanh(z @ pd_w^T + pd_b) -> X (padded weight cols >=100 are
      // zero -> junk z cols never propagate).
      gemm_mfma<2, false><<<dim3(RTM, 3), 512, 0, stream>>>(
          Z16, 256, 256, WB + WB_PD, 256, P[27], X, D_, mi);
    }
  }

  score_kernel<<<NP_, 256, 0, stream>>>(X, emean, Sv);
  finalize_kernel<<<1, 256, 0, stream>>>(Sv, mi, out);
  maskout_kernel<<<128, 256, 0, stream>>>(am, mi, out);
  newemb_kernel<<<B_ * T_ * L_, 192, 0, stream>>>(emb, mi, out);
}

// Round 11
// 2319.095 us; speedup vs baseline: 1.1458x; 1.1458x over previous
//
#include <hip/hip_runtime.h>
#include <hip/hip_bf16.h>
#include <math.h>

// ============================================================================
// ResponseFilter — round 13: revert to best-measured config (8-phase GEMM).
//
// Ledger: 8-phase GEMM (round-8 kernel) = 2302us BEST; de-serialized = 2385;
// 2 blk/CU = 2438; batched up-front weights = 2657 REGRESSION (per-dispatch
// w2bf into Wst was an accidental L2 prefetch of the weight panel; parking
// 44.8MB up-front made every layer's panel L2-cold -> gemm 140->170us).
// This round: (1) round-8 8-phase gemm_mfma verbatim (BK=64, 2x64KB dbuf,
// ONE counted vmcnt(2) per K-tile, per-phase stage||ds_read||MFMA interleave,
// setprio) + ACT=2 tanh epilogue; (2) per-dispatch w2bf into Wst restored;
// (3) pe/pd stay on MFMA (neutral, removes VALU gemm; K=768/256 mult of 64).
// attn / ln / gather / epilogues identical to verified code.
// ============================================================================

#define B_  16
#define T_  32
#define L_  64
#define D_  768
#define H_  12
#define F_  2048
#define ZR_ 100
#define NP_ 512
#define EPS_ 1e-5f

// meta int offsets (d_ws as int*)
#define MI_NTOT  0
#define MI_NRESP 8
#define MI_OFF   32
#define MI_BIDX  64
#define MI_TIDX  576
#define MI_NODE  1088

// ws float offsets
#define WS_BIAS2 2048
#define WS_EMEAN 34816
#define WS_S     428032
#define WS_WST   428544    // bf16 weight stage, 1,769,472 ushorts (3.54 MB)
#define WS_BIG   1313280   // bf16 QKV/hidden region; bf16 Z overlay (enc->dec)

// inside Wst (ushort offsets): pe padded weight, pd padded weight, pe bias pad
// (written at s==0 after the regular weights there are consumed; regular
// w2bf for s==1 overwrites only after pe/pd GEMMs are done)
#define WPE_OFF  0          // 256*768 = 196608 ushorts
#define WPD_OFF  196608     // 768*256 = 196608 ushorts
#define PEB_OFF  400000     // 256 floats (512 ushorts), 4B-aligned

// d_out float offsets (flat tuple: oh[512], ext_mask[32768], n_ext_adv[1],
// new_tree_lens[16], new_emb[25165824], new_msk[32768])
#define OUT_OH   0
#define OUT_EXT  512
#define OUT_NEA  33280
#define OUT_NTL  33281
#define OUT_NEMB 33297
#define OUT_NMSK 25199121
#define OUT_XSCR 33300   // bf16 X scratch (16B aligned), 32768*768 ushorts

typedef __attribute__((ext_vector_type(8))) short short8;
typedef __attribute__((ext_vector_type(4))) float f32x4;

__device__ inline float bf2f(unsigned s) {
  return __uint_as_float((s & 0xffffu) << 16);
}
__device__ inline unsigned short f2bf(float x) {
  unsigned u = __float_as_uint(x);
  u += 0x7fffu + ((u >> 16) & 1u);      // round-to-nearest-even
  return (unsigned short)(u >> 16);
}
__device__ inline unsigned pack2(float a, float b) {
  return (unsigned)f2bf(a) | ((unsigned)f2bf(b) << 16);
}

// ---------------------------------------------------------------------------
__global__ void meta_kernel(const int* __restrict__ tl, int* __restrict__ mi) {
  if (threadIdx.x != 0) return;
  int off = 0;
  for (int b = 0; b < B_; b++) {
    int nr = tl[b] - 1;
    mi[MI_NRESP + b] = nr;
    mi[MI_OFF + b] = off;
    off += nr;
  }
  mi[MI_NTOT] = off;
  for (int j = 0; j < NP_; j++) {
    int b = -1, t = 0;
    if (j < off) {
      b = 0;
      while (b + 1 < B_ && j >= mi[MI_OFF + b + 1]) b++;
      t = j - mi[MI_OFF + b] + 1;
    }
    mi[MI_BIDX + j] = b;
    mi[MI_TIDX + j] = t;
  }
}

// ---------------------------------------------------------------------------
// fp32 -> bf16 weight conversion (n multiple of 1024)
__global__ __launch_bounds__(256) void w2bf_kernel(const float* __restrict__ W,
                                                   unsigned short* __restrict__ o) {
  const int i = (blockIdx.x * 256 + threadIdx.x) * 4;
  float4 v = *(const float4*)(W + i);
  uint2 pk; pk.x = pack2(v.x, v.y); pk.y = pack2(v.z, v.w);
  *(uint2*)(o + i) = pk;
}

// fp32 [nr][nc] -> bf16 [NR][NC] zero-padded (NR*NC mult of 1024, NC mult 4)
__global__ __launch_bounds__(256) void padw2bf_kernel(
    const float* __restrict__ W, int nr, int nc,
    unsigned short* __restrict__ o, int NC) {
  const int e = (blockIdx.x * 256 + threadIdx.x) * 4;
  const int r = e / NC, c = e % NC;
  float v[4];
  #pragma unroll
  for (int j = 0; j < 4; j++)
    v[j] = (r < nr && c + j < nc) ? W[(size_t)r * nc + c + j] : 0.f;
  uint2 pk; pk.x = pack2(v[0], v[1]); pk.y = pack2(v[2], v[3]);
  *(uint2*)(o + e) = pk;
}

// pad bias to 256 floats (zeros beyond n)
__global__ void padbias_kernel(const float* __restrict__ b, int n,
                               float* __restrict__ o) {
  const int t = threadIdx.x;
  o[t] = (t < n) ? b[t] : 0.f;
}

// ---------------------------------------------------------------------------
// X[j,l,:] bf16 = reply embedding (zero for padded j); bias2 = mask or -1e30
__global__ __launch_bounds__(192) void gather_kernel(
    const float* __restrict__ emb, const float* __restrict__ am,
    const int* __restrict__ mi, unsigned short* __restrict__ X,
    float* __restrict__ bias2) {
  const int blk = blockIdx.x;          // j*64 + l
  const int j = blk >> 6, l = blk & 63;
  const int ntot = mi[MI_NTOT];
  const int t = threadIdx.x;
  float4 v = make_float4(0.f, 0.f, 0.f, 0.f);
  if (j < ntot) {
    const int b = mi[MI_BIDX + j], tt = mi[MI_TIDX + j];
    v = ((const float4*)(emb + (size_t)((b * T_ + tt) * L_ + l) * D_))[t];
    if (t == 0) bias2[blk] = am[(b * T_ + tt) * L_ + l];
  } else {
    if (t == 0) bias2[blk] = -1e30f;
  }
  uint2 pk; pk.x = pack2(v.x, v.y); pk.y = pack2(v.z, v.w);
  *(uint2*)(X + (size_t)blk * D_ + t * 4) = pk;
}

// ---------------------------------------------------------------------------
__global__ __launch_bounds__(256) void emean_kernel(const unsigned short* __restrict__ X,
                                                    float* __restrict__ em) {
  const int j = blockIdx.x;
  int d = threadIdx.x;
  for (int c = 0; c < 3; c++, d += 256) {
    const unsigned short* p = X + (size_t)j * L_ * D_ + d;
    float s = 0.f;
    for (int l = 0; l < L_; l++) s += bf2f(p[l * D_]);
    em[j * D_ + d] = s * (1.f / 64.f);
  }
}

// ---------------------------------------------------------------------------
__device__ inline float blockSum256(float v, float* red) {
  #pragma unroll
  for (int o = 32; o > 0; o >>= 1) v += __shfl_down(v, o);
  const int lane = threadIdx.x & 63, wid = threadIdx.x >> 6;
  __syncthreads();
  if (lane == 0) red[wid] = v;
  __syncthreads();
  return red[0] + red[1] + red[2] + red[3];
}

// in-place LN, wave-per-row (4 rows/block, no barriers); skips padded rows
__global__ __launch_bounds__(256) void ln_kernel(unsigned short* __restrict__ X,
                                                 const float* __restrict__ g,
                                                 const float* __restrict__ bb,
                                                 const int* __restrict__ mi) {
  const int row = blockIdx.x * 4 + (threadIdx.x >> 6);
  if (row >= mi[MI_NTOT] * L_) return;
  const int lane = threadIdx.x & 63;
  unsigned short* p = X + (size_t)row * D_;
  float v[12];
  #pragma unroll
  for (int c = 0; c < 3; c++) {
    uint2 u = *(const uint2*)(p + lane * 4 + c * 256);
    v[c * 4 + 0] = bf2f(u.x); v[c * 4 + 1] = bf2f(u.x >> 16);
    v[c * 4 + 2] = bf2f(u.y); v[c * 4 + 3] = bf2f(u.y >> 16);
  }
  float s = 0.f;
  #pragma unroll
  for (int i = 0; i < 12; i++) s += v[i];
  #pragma unroll
  for (int o = 32; o > 0; o >>= 1) s += __shfl_xor(s, o);
  const float m = s * (1.f / 768.f);
  float q = 0.f;
  #pragma unroll
  for (int i = 0; i < 12; i++) { v[i] -= m; q += v[i] * v[i]; }
  #pragma unroll
  for (int o = 32; o > 0; o >>= 1) q += __shfl_xor(q, o);
  const float r = rsqrtf(q * (1.f / 768.f) + EPS_);
  #pragma unroll
  for (int c = 0; c < 3; c++) {
    const int d = lane * 4 + c * 256;
    float4 gv = *(const float4*)(g + d);
    float4 bv = *(const float4*)(bb + d);
    uint2 pk;
    pk.x = pack2(v[c * 4 + 0] * r * gv.x + bv.x, v[c * 4 + 1] * r * gv.y + bv.y);
    pk.y = pack2(v[c * 4 + 2] * r * gv.z + bv.z, v[c * 4 + 3] * r * gv.w + bv.w);
    *(uint2*)(p + d) = pk;
  }
}

// ---------------------------------------------------------------------------
// MFMA bf16 GEMM, 8-phase schedule (best-measured): C = [C +] act(A@W^T + b).
// 256x256 tile, 512 thr (8 waves 2x4, wave tile 128x64). K mult of 64,
// N mult of 256. BK=64, 2 K-tile LDS dbufs (128 KB): A[256][64] + B[256][64]
// bf16 per buffer, row = 128 B, chunk slot s of row r holds k-chunk s^(r&7).
// Per K-tile, 4 phases x {stage 1 half-tile || ds_read subtile -> barrier ->
// lgkmcnt(0)+sched_barrier -> setprio(1) 16 MFMA setprio(0) -> barrier};
// one vmcnt(2) per K-tile at phase 0 (counted; vmcnt(0) only on last tile).
// B-frags (8 ds_read) register-resident per K-tile; A-frags 4/phase.
// ACT: 0 none, 1 relu, 2 tanh. Epilogue: two 64x64 passes via per-wave 8KB
// LDS slice -> coalesced short8 stores (+ residual add at readback for ADD).
template <int ACT, bool ADD>
__global__ __launch_bounds__(512) void gemm_mfma(
    const unsigned short* __restrict__ A, int lda, int K,
    const unsigned short* __restrict__ W, int ldw,
    const float* __restrict__ bias,
    unsigned short* __restrict__ C, int ldc,
    const int* __restrict__ mi) {
  const int rows = mi[MI_NTOT] * 64;
  const int row0 = blockIdx.x * 256;
  if (row0 >= rows) return;
  const int col0 = blockIdx.y * 256;
  __shared__ unsigned short Sh[2 * 32768];   // 2 dbuf x (A 32KB + B 32KB) = 128KB
  const int t = threadIdx.x;
  const int lane = t & 63, w = t >> 6;        // 8 waves
  const int wr = w >> 2, wc = w & 3;          // 2x4 wave grid, tile 128x64
  const int quad = lane >> 4, l15 = lane & 15;
  f32x4 acc[8][4];
  #pragma unroll
  for (int i = 0; i < 8; i++)
    #pragma unroll
    for (int j = 0; j < 4; j++) acc[i][j] = (f32x4){0.f, 0.f, 0.f, 0.f};

  // staging per-thread constants: thread covers rows h*128 + j*64 + sr,
  // slot s = lane&7 holds global k-chunk s ^ (lane>>3)  (row&7 == lane>>3)
  const int sr  = w * 8 + (lane >> 3);
  const int cc8 = ((lane & 7) ^ (lane >> 3)) * 8;

  // fragment ds_read offsets (ushort units); row*64 + slot*8, slot = c^(r&7)
  int aoffm[8], boffn[4];
  #pragma unroll
  for (int m = 0; m < 8; m++) aoffm[m] = (wr * 128 + m * 16 + l15) * 64;
  #pragma unroll
  for (int n = 0; n < 4; n++) boffn[n] = (wc * 64 + n * 16 + l15) * 64;
  const int e7 = l15 & 7;
  const int pq0 = ((quad)     ^ e7) * 8;     // kc=0 chunk slot
  const int pq1 = ((4 + quad) ^ e7) * 8;     // kc=1 chunk slot

  // stage half h (0/1) of matrix (0=A,1=B) for K-tile kt into buffer bi
#define STG(bi_, mat_, h_, kt_)                                                \
  { const unsigned short* gp_ = (mat_) ? W : A;                                \
    const int ld_ = (mat_) ? ldw : lda;                                        \
    const int b0_ = (mat_) ? col0 : row0;                                      \
    _Pragma("unroll")                                                          \
    for (int j_ = 0; j_ < 2; j_++) {                                           \
      const unsigned short* src_ =                                             \
          gp_ + (size_t)(b0_ + (h_) * 128 + j_ * 64 + sr) * ld_ +              \
          (kt_) * 64 + cc8;                                                    \
      __builtin_amdgcn_global_load_lds(                                        \
          (const __attribute__((address_space(1))) void*)src_,                 \
          (__attribute__((address_space(3))) void*)(Sh + (bi_) * 32768 +       \
              (mat_) * 16384 + (h_) * 8192 + j_ * 4096 + w * 512),             \
          16, 0, 0);                                                           \
    } }

  const int NT = K >> 6;     // 64-k tiles (call sites: 4, 12 or 32)
  // prologue: tile 0 into buf 0 (8 loads/thread)
  STG(0, 0, 0, 0); STG(0, 0, 1, 0); STG(0, 1, 0, 0); STG(0, 1, 1, 0);

  for (int kt = 0; kt < NT; kt++) {
    const int cur = kt & 1, nxt = cur ^ 1;
    const unsigned short* SA = Sh + cur * 32768;
    const unsigned short* SB = SA + 16384;
    const bool more = (kt + 1 < NT);
    short8 bfr[4][2];
    #pragma unroll
    for (int p = 0; p < 4; p++) {
      // ---- stage one half-tile of the next K-tile
      if (more) {
        if      (p == 0) STG(nxt, 0, 0, kt + 1)
        else if (p == 1) STG(nxt, 0, 1, kt + 1)
        else if (p == 2) STG(nxt, 1, 0, kt + 1)
        else             STG(nxt, 1, 1, kt + 1)
      }
      if (p == 0) {
        // counted wait: older 8 loads (this tile) retire; the 2 just-issued
        // stay in flight. Barrier makes cross-wave staging visible.
        if (more) asm volatile("s_waitcnt vmcnt(2)" ::: "memory");
        else      asm volatile("s_waitcnt vmcnt(0)" ::: "memory");
        __builtin_amdgcn_s_barrier();
      }
      // ---- ds_read subtile
      short8 afr[2][2];
      if (p == 0) {
        #pragma unroll
        for (int n = 0; n < 4; n++) {
          bfr[n][0] = *(const short8*)(SB + boffn[n] + pq0);
          bfr[n][1] = *(const short8*)(SB + boffn[n] + pq1);
        }
      }
      #pragma unroll
      for (int i = 0; i < 2; i++) {
        afr[i][0] = *(const short8*)(SA + aoffm[2 * p + i] + pq0);
        afr[i][1] = *(const short8*)(SA + aoffm[2 * p + i] + pq1);
      }
      if (p != 0) __builtin_amdgcn_s_barrier();
      asm volatile("s_waitcnt lgkmcnt(0)" ::: "memory");
      __builtin_amdgcn_sched_barrier(0);
      // ---- MFMA cluster (16)
      __builtin_amdgcn_s_setprio(1);
      #pragma unroll
      for (int i = 0; i < 2; i++)
        #pragma unroll
        for (int n = 0; n < 4; n++) {
          acc[2 * p + i][n] = __builtin_amdgcn_mfma_f32_16x16x32_bf16(
              afr[i][0], bfr[n][0], acc[2 * p + i][n], 0, 0, 0);
          acc[2 * p + i][n] = __builtin_amdgcn_mfma_f32_16x16x32_bf16(
              afr[i][1], bfr[n][1], acc[2 * p + i][n], 0, 0, 0);
        }
      __builtin_amdgcn_s_setprio(0);
      __builtin_amdgcn_s_barrier();
    }
  }
  __syncthreads();           // LDS now dead -> reuse as epilogue bounce
#undef STG

  // epilogue: C/D layout col = lane&15, row = quad*4 + reg. Two 64x64 passes
  // per wave through its private 8KB slice, then coalesced short8 stores
  // (8 per lane per pass). Residual add (ADD) at readback.
  unsigned short* slice = Sh + w * 4096;
  float bv[4];
  #pragma unroll
  for (int n = 0; n < 4; n++) bv[n] = bias[col0 + wc * 64 + n * 16 + l15];
  #pragma unroll
  for (int p = 0; p < 2; p++) {
    #pragma unroll
    for (int mm = 0; mm < 4; mm++) {
      #pragma unroll
      for (int reg = 0; reg < 4; reg++) {
        const int r64 = mm * 16 + quad * 4 + reg;
        #pragma unroll
        for (int n = 0; n < 4; n++) {
          float x = acc[p * 4 + mm][n][reg] + bv[n];
          if (ACT == 1) x = fmaxf(x, 0.f);
          if (ACT == 2) x = tanhf(x);
          slice[r64 * 64 + n * 16 + l15] = f2bf(x);
        }
      }
    }
    unsigned short* crow =
        C + (size_t)(row0 + wr * 128 + p * 64) * ldc + col0 + wc * 64;
    #pragma unroll
    for (int i = 0; i < 8; i++) {
      const int j = i * 64 + lane;           // 16B chunk 0..511 of 64x64 tile
      const int r64 = j >> 3, c8 = (j & 7) * 8;
      short8 v = *(const short8*)(slice + j * 8);
      unsigned short* cp = crow + (size_t)r64 * ldc + c8;
      if (ADD) {
        short8 cv = *(const short8*)cp;
        #pragma unroll
        for (int e = 0; e < 8; e++)
          v[e] = (short)f2bf(bf2f((unsigned short)v[e]) +
                             bf2f((unsigned short)cv[e]));
      }
      *(short8*)cp = v;
    }
  }
}

// ---------------------------------------------------------------------------
// MFMA attention, KV-resident: one block per (l, h), 8 waves (512 thr).
// Stage ALL K (global_load_lds, pre-swizzled source -> linear LDS) and V^T
// (manual transpose scatter) once; single barrier; then each wave free-runs
// q-tiles (16 rows/wave, 128/block) x kv-tiles with zero global loads and
// zero barriers (P staging per-wave). O bf16 overwrites Q columns of QKV
// (disjoint from staged K/V columns; each wave owns its rows -> race-free).
// LDS tile swizzle: elem(row,col) at row*64 + ((col>>3)^(row&7))*8 + (col&7).
__global__ __launch_bounds__(512) void attn_kernel(
    unsigned short* __restrict__ QKV, const float* __restrict__ bias2,
    const int* __restrict__ mi) {
  const int ntot = mi[MI_NTOT];
  const int l = blockIdx.x, h = blockIdx.y;
  const int ntk = (ntot + 63) >> 6;     // kv tiles (padded keys masked by bias)
  __shared__ unsigned short Ks[512 * 64];   // K rows [m][d], swizzled
  __shared__ unsigned short Vt[8 * 4096];   // per-tile V^T [d][m], swizzled
  __shared__ unsigned short Ps[8][1024];    // per-wave P / O-bounce
  __shared__ float bs[512];                 // bias column for this l
  const int t = threadIdx.x;
  const int lane = t & 63, w = t >> 6;
  const int quad = lane >> 4, l15 = lane & 15;

  // ---- stage K: linear LDS dst, source chunk pre-swizzled so slot g of row
  // m holds chunk g ^ (m&7) (matches the ds_read swizzle below)
  {
    const int sub = lane >> 3;              // low 3 bits of m
    const int cc = (lane & 7) ^ sub;        // source chunk for this slot
    for (int it = 0; it < ntk; it++) {
      const int m = it * 64 + w * 8 + sub;
      const unsigned short* src =
          QKV + (size_t)(m * L_ + l) * 2304 + 768 + h * 64 + cc * 8;
      __builtin_amdgcn_global_load_lds(
          (const __attribute__((address_space(1))) void*)src,
          (__attribute__((address_space(3))) void*)(Ks + it * 4096 + w * 512),
          16, 0, 0);
    }
  }
  // ---- stage V transposed: thread t -> m = t&63, d in [(t>>6)*8, +8)
  {
    const int m = t & 63;
    const int d0 = (t >> 6) * 8;
    for (int mt = 0; mt < ntk; mt++) {
      short8 v = *(const short8*)(
          QKV + (size_t)((mt * 64 + m) * L_ + l) * 2304 + 1536 + h * 64 + d0);
      #pragma unroll
      for (int i = 0; i < 8; i++) {
        const int d = d0 + i;
        Vt[mt * 4096 + d * 64 + (((m >> 3) ^ (d & 7)) * 8) + (m & 7)] =
            (unsigned short)v[i];
      }
    }
  }
  // ---- stage bias column (padded m already -1e30 from gather)
  bs[t] = bias2[t * 64 + l];
  __syncthreads();

  const int nqt = (ntot + 127) >> 7;
  for (int qt = 0; qt < nqt; qt++) {
    const int qbase = qt * 128 + w * 16;
    if (qbase >= ntot) continue;

    // Q A-frags direct from global (2 x 16B per lane)
    short8 af[2];
    #pragma unroll
    for (int kc = 0; kc < 2; kc++)
      af[kc] = *(const short8*)(
          QKV + (size_t)((qbase + l15) * L_ + l) * 2304 + h * 64 + (kc * 4 + quad) * 8);

    f32x4 oa[4];
    float runmax[4], runsum[4];
    #pragma unroll
    for (int f = 0; f < 4; f++) oa[f] = (f32x4){0.f, 0.f, 0.f, 0.f};
    #pragma unroll
    for (int r2 = 0; r2 < 4; r2++) { runmax[r2] = -3.0e38f; runsum[r2] = 0.f; }

    for (int mt = 0; mt < ntk; mt++) {
      // ---- S = Q @ K^T  (C layout: row q = quad*4+reg, col m = cb*16+l15)
      f32x4 sv[4];
      #pragma unroll
      for (int cb = 0; cb < 4; cb++) {
        sv[cb] = (f32x4){0.f, 0.f, 0.f, 0.f};
        const int mrow = mt * 64 + cb * 16 + l15;
        #pragma unroll
        for (int kc = 0; kc < 2; kc++) {
          short8 bk = *(const short8*)(
              Ks + mrow * 64 + (((kc * 4 + quad) ^ (mrow & 7)) * 8));
          sv[cb] = __builtin_amdgcn_mfma_f32_16x16x32_bf16(af[kc], bk, sv[cb], 0, 0, 0);
        }
      }

      // ---- online softmax (state per q-row = quad*4+reg)
      float bj[4];
      #pragma unroll
      for (int cb = 0; cb < 4; cb++) bj[cb] = bs[mt * 64 + cb * 16 + l15];
      float pj[4][4];   // [cb][reg]
      #pragma unroll
      for (int cb = 0; cb < 4; cb++)
        #pragma unroll
        for (int r2 = 0; r2 < 4; r2++) pj[cb][r2] = sv[cb][r2] * 0.125f + bj[cb];
      float tmax[4];
      #pragma unroll
      for (int r2 = 0; r2 < 4; r2++)
        tmax[r2] = fmaxf(fmaxf(pj[0][r2], pj[1][r2]), fmaxf(pj[2][r2], pj[3][r2]));
      #pragma unroll
      for (int o2 = 1; o2 < 16; o2 <<= 1)
        #pragma unroll
        for (int r2 = 0; r2 < 4; r2++) tmax[r2] = fmaxf(tmax[r2], __shfl_xor(tmax[r2], o2));
      float tsum[4];
      #pragma unroll
      for (int r2 = 0; r2 < 4; r2++) {
        const float nmax = fmaxf(runmax[r2], tmax[r2]);
        const float alpha = __expf(runmax[r2] - nmax);
        runmax[r2] = nmax;
        float s0 = 0.f;
        #pragma unroll
        for (int cb = 0; cb < 4; cb++) { pj[cb][r2] = __expf(pj[cb][r2] - nmax); s0 += pj[cb][r2]; }
        tsum[r2] = s0;
        runsum[r2] *= alpha;
        #pragma unroll
        for (int f = 0; f < 4; f++) oa[f][r2] *= alpha;
      }
      #pragma unroll
      for (int o2 = 1; o2 < 16; o2 <<= 1)
        #pragma unroll
        for (int r2 = 0; r2 < 4; r2++) tsum[r2] += __shfl_xor(tsum[r2], o2);
      #pragma unroll
      for (int r2 = 0; r2 < 4; r2++) runsum[r2] += tsum[r2];

      // ---- P -> per-wave LDS (A-operand layout, bf16)
      #pragma unroll
      for (int cb = 0; cb < 4; cb++) {
        const int m = cb * 16 + l15;
        #pragma unroll
        for (int r2 = 0; r2 < 4; r2++) {
          const int q = quad * 4 + r2;
          Ps[w][q * 64 + (((m >> 3) ^ (q & 7)) * 8) + (m & 7)] = f2bf(pj[cb][r2]);
        }
      }
      // ---- O += P @ V
      short8 pa[2];
      #pragma unroll
      for (int kc = 0; kc < 2; kc++)
        pa[kc] = *(const short8*)(
            &Ps[w][l15 * 64 + (((kc * 4 + quad) ^ (l15 & 7)) * 8)]);
      #pragma unroll
      for (int f = 0; f < 4; f++) {
        const int d = f * 16 + l15;
        #pragma unroll
        for (int kc = 0; kc < 2; kc++) {
          short8 bv = *(const short8*)(
              Vt + mt * 4096 + d * 64 + (((kc * 4 + quad) ^ (d & 7)) * 8));
          oa[f] = __builtin_amdgcn_mfma_f32_16x16x32_bf16(pa[kc], bv, oa[f], 0, 0, 0);
        }
      }
    }

    // ---- epilogue: normalize, bounce through per-wave Ps, 16B stores
    #pragma unroll
    for (int r2 = 0; r2 < 4; r2++) {
      const float inv = 1.f / runsum[r2];
      const int q = quad * 4 + r2;
      #pragma unroll
      for (int f = 0; f < 4; f++)
        Ps[w][q * 64 + f * 16 + l15] = f2bf(oa[f][r2] * inv);
    }
    #pragma unroll
    for (int i = 0; i < 2; i++) {
      const int j = lane + i * 64;          // 16B chunk index 0..127
      const int q = j >> 3, c8 = j & 7;
      short8 v = *(const short8*)(&Ps[w][j * 8]);
      *(short8*)(QKV + (size_t)((qbase + q) * L_ + l) * 2304 + h * 64 + c8 * 8) = v;
    }
  }
}

// ---------------------------------------------------------------------------
__global__ __launch_bounds__(256) void score_kernel(const unsigned short* __restrict__ X,
                                                    const float* __restrict__ em,
                                                    float* __restrict__ Sv) {
  const int j = blockIdx.x;
  const int t = threadIdx.x;
  __shared__ float red[4];
  float part = 0.f;
  for (int c = 0; c < 3; c++) {
    const int d = t + c * 256;
    const unsigned short* p = X + (size_t)j * L_ * D_ + d;
    float s = 0.f;
    for (int l = 0; l < L_; l++) s += bf2f(p[l * D_]);
    const float diff = s * (1.f / 64.f) - em[j * D_ + d];
    part += diff * diff;
  }
  const float tot = blockSum256(part, red);
  if (t == 0) Sv[j] = tot;
}

// ---------------------------------------------------------------------------
__global__ __launch_bounds__(256) void finalize_kernel(const float* __restrict__ Sv,
                                                       int* __restrict__ mi,
                                                       float* __restrict__ out) {
  const int t = threadIdx.x;
  if (t < B_) {
    const int nr = mi[MI_NRESP + t];
    float best = 3.0e38f; int bi = 0;
    for (int j = 0; j < nr; j++) {
      const float v = Sv[j];
      if (v < best) { best = v; bi = j; }
    }
    mi[MI_NODE + t] = bi + 1;
    int next = nr / 20; if (next < 1) next = 1;
    out[OUT_NTL + t] = (float)(1 + next);
  }
  if (t == 0) out[OUT_NEA] = 0.f;
  __syncthreads();
  for (int idx = t; idx < B_ * T_; idx += 256) {
    const int b = idx >> 5, tt = idx & 31;
    out[OUT_OH + idx] = (tt == 0 || tt == mi[MI_NODE + b]) ? 1.f : 0.f;
  }
}

// ---------------------------------------------------------------------------
__global__ __launch_bounds__(256) void maskout_kernel(const float* __restrict__ am,
                                                      const int* __restrict__ mi,
                                                      float* __restrict__ out) {
  const int idx = blockIdx.x * 256 + threadIdx.x;
  const int b = idx >> 11, rem = idx & 2047;
  const int tt = rem >> 6, l = rem & 63;
  const int node = mi[MI_NODE + b];
  out[OUT_EXT + idx] = (tt == 0 || tt == node) ? 1.f : 0.f;
  float nm;
  if (tt == 0)      nm = am[(b * T_) * L_ + l];
  else if (tt == 1) nm = am[(b * T_ + node) * L_ + l];
  else              nm = 0.f;
  out[OUT_NMSK + idx] = nm;
}

// ---------------------------------------------------------------------------
__global__ __launch_bounds__(192) void newemb_kernel(const float* __restrict__ emb,
                                                     const int* __restrict__ mi,
                                                     float* __restrict__ out) {
  const int blk = blockIdx.x;
  const int b = blk >> 11, rem = blk & 2047;
  const int tt = rem >> 6, l = rem & 63;
  const int srct = (tt == 1) ? mi[MI_NODE + b] : 0;
  const float4 v = ((const float4*)(emb + (size_t)((b * T_ + srct) * L_ + l) * D_))[threadIdx.x];
  float* dst = out + OUT_NEMB + (size_t)blk * D_ + threadIdx.x * 4;
  dst[0] = v.x; dst[1] = v.y; dst[2] = v.z; dst[3] = v.w;
}

// ===========================================================================
extern "C" void kernel_launch(void* const* d_in, const int* in_sizes, int n_in,
                              void* d_out, int out_size, void* d_ws, size_t ws_size,
                              hipStream_t stream) {
  (void)in_sizes; (void)n_in; (void)out_size; (void)ws_size;
  const int*   tl  = (const int*)d_in[0];
  const float* emb = (const float*)d_in[1];
  const float* am  = (const float*)d_in[2];
  const float* P[28];
  for (int i = 0; i < 28; i++) P[i] = (const float*)d_in[3 + i];

  float* wsf   = (float*)d_ws;
  int*   mi    = (int*)d_ws;
  float* bias2 = wsf + WS_BIAS2;
  float* emean = wsf + WS_EMEAN;
  float* Sv    = wsf + WS_S;
  unsigned short* Wst = (unsigned short*)(wsf + WS_WST);
  unsigned short* BIG = (unsigned short*)(wsf + WS_BIG);
  unsigned short* Z16 = BIG;                        // bf16 Z overlay (enc->dec)
  float* out   = (float*)d_out;
  unsigned short* X = (unsigned short*)(out + OUT_XSCR);  // bf16 residual

  meta_kernel<<<1, 64, 0, stream>>>(tl, mi);
  gather_kernel<<<NP_ * L_, 192, 0, stream>>>(emb, am, mi, X, bias2);
  emean_kernel<<<NP_, 256, 0, stream>>>(X, emean);

  const int RTM = NP_ * 64 / 256;  // 128 row tiles (256 rows each)
  const int LNB = NP_ * L_ / 4;    // 8192 ln blocks (4 rows each)
  for (int s = 0; s < 2; s++) {
    const float* const* q = P + s * 12;
    for (int i = 0; i < 2; i++) {
      // QKV: X -> BIG [rows, 2304]
      w2bf_kernel<<<(3 * D_ * D_) / 1024, 256, 0, stream>>>(q[0] + (size_t)i * 3 * D_ * D_, Wst);
      gemm_mfma<0, false><<<dim3(RTM, 9), 512, 0, stream>>>(
          X, D_, D_, Wst, D_, q[1] + i * 3 * D_, BIG, 3 * D_, mi);
      attn_kernel<<<dim3(L_, H_), 512, 0, stream>>>(BIG, bias2, mi);
      // out-proj: O (Q cols of BIG, lda=2304) -> += X
      w2bf_kernel<<<(D_ * D_) / 1024, 256, 0, stream>>>(q[2] + (size_t)i * D_ * D_, Wst);
      gemm_mfma<0, true><<<dim3(RTM, 3), 512, 0, stream>>>(
          BIG, 3 * D_, D_, Wst, D_, q[3] + i * D_, X, D_, mi);
      ln_kernel<<<LNB, 256, 0, stream>>>(X, q[4] + i * D_, q[5] + i * D_, mi);
      // FFN1: X -> hidden BIG [rows, 2048] (relu)
      w2bf_kernel<<<(F_ * D_) / 1024, 256, 0, stream>>>(q[6] + (size_t)i * F_ * D_, Wst);
      gemm_mfma<1, false><<<dim3(RTM, 8), 512, 0, stream>>>(
          X, D_, D_, Wst, D_, q[7] + i * F_, BIG, F_, mi);
      // FFN2: hidden -> += X
      w2bf_kernel<<<(D_ * F_) / 1024, 256, 0, stream>>>(q[8] + (size_t)i * D_ * F_, Wst);
      gemm_mfma<0, true><<<dim3(RTM, 3), 512, 0, stream>>>(
          BIG, F_, F_, Wst, F_, q[9] + i * D_, X, D_, mi);
      ln_kernel<<<LNB, 256, 0, stream>>>(X, q[10] + i * D_, q[11] + i * D_, mi);
    }
    if (s == 0) {
      // pe: z = tanh(X @ pe_w^T + pe_b) via MFMA, padded N=256 (rows >=100
      // of padded weight are zero, pad bias zero -> padded z cols = 0).
      // Z16 bf16 [rows][256] overlays BIG (dead FFN-hidden here).
      padw2bf_kernel<<<(256 * D_) / 1024, 256, 0, stream>>>(
          P[24], ZR_, D_, Wst + WPE_OFF, D_);
      padw2bf_kernel<<<(D_ * 256) / 1024, 256, 0, stream>>>(
          P[26], D_, ZR_, Wst + WPD_OFF, 256);
      padbias_kernel<<<1, 256, 0, stream>>>(P[25], ZR_, (float*)(Wst + PEB_OFF));
      gemm_mfma<2, false><<<dim3(RTM, 1), 512, 0, stream>>>(
          X, D_, D_, Wst + WPE_OFF, D_, (const float*)(Wst + PEB_OFF),
          Z16, 256, mi);
      // pd: zd = tanh(z @ pd_w^T + pd_b) -> X (padded weight cols >=100 are
      // zero -> junk z cols never propagate).
      gemm_mfma<2, false><<<dim3(RTM, 3), 512, 0, stream>>>(
          Z16, 256, 256, Wst + WPD_OFF, 256, P[27], X, D_, mi);
    }
  }

  score_kernel<<<NP_, 256, 0, stream>>>(X, emean, Sv);
  finalize_kernel<<<1, 256, 0, stream>>>(Sv, mi, out);
  maskout_kernel<<<128, 256, 0, stream>>>(am, mi, out);
  newemb_kernel<<<B_ * T_ * L_, 192, 0, stream>>>(emb, mi, out);
}